// Round 1
// baseline (2081.112 us; speedup 1.0000x reference)
//
#include <hip/hip_runtime.h>
#include <hip/hip_fp16.h>
#include <cstdint>
#include <cstddef>

#define SEQ   128
#define BATCH 256
#define HDIM  1024
#define ODIM  128

typedef _Float16 half_t;
typedef _Float16 half8 __attribute__((ext_vector_type(8)));
typedef float    f32x4 __attribute__((ext_vector_type(4)));

__device__ __forceinline__ float sigmoidf_(float z) {
    return 1.0f / (1.0f + __expf(-z));
}
__device__ __forceinline__ float tanhf_(float z) {
    // clamp to avoid exp overflow; tanh saturates well before |30|
    z = fminf(fmaxf(z, -30.0f), 30.0f);
    float e = __expf(2.0f * z);
    return (e - 1.0f) / (e + 1.0f);
}

// ---------------------------------------------------------------------------
// Init: Wh (4x 1024x1024 fp32) -> f16 gate-major [g][u][k]; fused bias
// (bx+bh) and x-weight per gate-unit; zero h0 (f16) and c (fp32).
// Re-run every call: harness re-poisons d_ws to 0xAA before each timed launch.
// ---------------------------------------------------------------------------
__global__ __launch_bounds__(256) void lstm_init(
    const float* __restrict__ Wfh, const float* __restrict__ Wih,
    const float* __restrict__ Wgh, const float* __restrict__ Woh,
    const float* __restrict__ Wfx, const float* __restrict__ Wix,
    const float* __restrict__ Wgx, const float* __restrict__ Wox,
    const float* __restrict__ bfx, const float* __restrict__ bix,
    const float* __restrict__ bgx, const float* __restrict__ box,
    const float* __restrict__ bfh, const float* __restrict__ bih,
    const float* __restrict__ bgh, const float* __restrict__ boh,
    half_t* __restrict__ Whh, half_t* __restrict__ h0, float* __restrict__ c,
    float* __restrict__ bias, float* __restrict__ wx)
{
    const int tid = blockIdx.x * blockDim.x + threadIdx.x;
    const int nth = gridDim.x * blockDim.x;

    // fp32 -> f16 weight conversion, 4 elements per iteration
    for (int i = tid; i < (4 * HDIM * HDIM) / 4; i += nth) {
        const int e = i * 4;
        const int g = e >> 20;                 // 1M elements per gate
        const int r = e & ((1 << 20) - 1);
        const float* src = (g == 0) ? Wfh : (g == 1) ? Wih : (g == 2) ? Wgh : Woh;
        const float4 v = ((const float4*)src)[r >> 2];
        half_t* dst = Whh + e;
        dst[0] = (half_t)v.x; dst[1] = (half_t)v.y;
        dst[2] = (half_t)v.z; dst[3] = (half_t)v.w;
    }

    int4 z4; z4.x = z4.y = z4.z = z4.w = 0;
    for (int i = tid; i < (BATCH * HDIM) / 8; i += nth) ((int4*)h0)[i] = z4;  // f16 zeros
    for (int i = tid; i < (BATCH * HDIM) / 4; i += nth) ((int4*)c)[i]  = z4;  // fp32 zeros

    for (int i = tid; i < 4 * HDIM; i += nth) {
        const int g = i >> 10, u = i & (HDIM - 1);
        const float* bx  = (g == 0) ? bfx : (g == 1) ? bix : (g == 2) ? bgx : box;
        const float* bh  = (g == 0) ? bfh : (g == 1) ? bih : (g == 2) ? bgh : boh;
        const float* wxs = (g == 0) ? Wfx : (g == 1) ? Wix : (g == 2) ? Wgx : Wox;
        bias[i] = bx[u] + bh[u];
        wx[i]   = wxs[u];       // W?x has shape (H,1) -> element u
    }
}

// ---------------------------------------------------------------------------
// One LSTM step. Grid (4, 64): blockIdx.x = batch-tile (64 rows),
// blockIdx.y = hidden-unit tile (16 u). 4 waves; wave w owns batch rows
// m0..m0+15 and all 4 gates for the 16 u. f,i,g,o for a given (b,u) land in
// the same lane (C/D: row=(lane>>4)*4+reg, col=lane&15) -> thread-local gate
// fusion. B staged via LDS in [kchunk][row] order (<=2-way bank aliasing,
// free). A (h) read directly from L2 (h = 512 KB, cache-resident).
// h double-buffered across steps: blocks read other blocks' h slices.
// ---------------------------------------------------------------------------
__global__ __launch_bounds__(256) void lstm_step(
    int t, const float* __restrict__ x,
    const half_t* __restrict__ Whh, const float* __restrict__ bias,
    const float* __restrict__ wx,
    const half_t* __restrict__ hin, half_t* __restrict__ hout,
    float* __restrict__ c)
{
    __shared__ half_t Btile[4 * 64 * 8];    // [q(4 k-chunks of 8)][row(64)][8] = 4 KB

    const int tid  = threadIdx.x;
    const int w    = tid >> 6;
    const int lane = tid & 63;
    const int l15  = lane & 15;
    const int q    = lane >> 4;

    const int m0 = (blockIdx.x << 6) + (w << 4);   // wave's batch-row base
    const int u0 = blockIdx.y << 4;                // hidden-unit base

    f32x4 acc0 = {0.f, 0.f, 0.f, 0.f};
    f32x4 acc1 = acc0, acc2 = acc0, acc3 = acc0;

    // Staging: wave w loads k-subchunk w (8 halves) for all 64 rows (4 gate strips)
    const int sg = lane >> 4, sdu = lane & 15;
    const half_t* gsrc = Whh + (((size_t)(sg * HDIM + u0 + sdu)) << 10) + (w << 3);
    int4* lds_dst = (int4*)&Btile[(w * 64 + lane) * 8];

    // A fragment: A[m = lane&15][k = kk + (lane>>4)*8 + j]
    const half_t* asrc = hin + (((size_t)(m0 + l15)) << 10) + (q << 3);

    for (int kk = 0; kk < HDIM; kk += 32) {
        const int4  sv = *(const int4*)(gsrc + kk);
        const half8 av = *(const half8*)(asrc + kk);
        __syncthreads();              // prior iteration's LDS reads complete
        *lds_dst = sv;
        __syncthreads();              // staged tile visible
        const half8* bt = (const half8*)&Btile[(q * 64) * 8];
        const half8 b0 = bt[ 0 + l15];
        const half8 b1 = bt[16 + l15];
        const half8 b2 = bt[32 + l15];
        const half8 b3 = bt[48 + l15];
        acc0 = __builtin_amdgcn_mfma_f32_16x16x32_f16(av, b0, acc0, 0, 0, 0);
        acc1 = __builtin_amdgcn_mfma_f32_16x16x32_f16(av, b1, acc1, 0, 0, 0);
        acc2 = __builtin_amdgcn_mfma_f32_16x16x32_f16(av, b2, acc2, 0, 0, 0);
        acc3 = __builtin_amdgcn_mfma_f32_16x16x32_f16(av, b3, acc3, 0, 0, 0);
    }

    // Fused gate epilogue: z = acc + x_t*wx + (bx+bh); c,h update
    const int u = u0 + l15;
    const float bf = bias[0 * HDIM + u], bi = bias[1 * HDIM + u];
    const float bg = bias[2 * HDIM + u], bo = bias[3 * HDIM + u];
    const float wf = wx[0 * HDIM + u],  wi = wx[1 * HDIM + u];
    const float wg = wx[2 * HDIM + u],  wo = wx[3 * HDIM + u];
#pragma unroll
    for (int r = 0; r < 4; ++r) {
        const int b = m0 + q * 4 + r;          // C/D row = (lane>>4)*4 + reg
        const float xv = x[t * BATCH + b];
        const float zf = acc0[r] + xv * wf + bf;
        const float zi = acc1[r] + xv * wi + bi;
        const float zg = acc2[r] + xv * wg + bg;
        const float zo = acc3[r] + xv * wo + bo;
        const float fg = sigmoidf_(zf);
        const float ig = sigmoidf_(zi);
        const float gg = tanhf_(zg);
        const float og = sigmoidf_(zo);
        const size_t idx = ((size_t)b << 10) + u;
        const float cn = gg * ig + c[idx] * fg;
        c[idx] = cn;
        hout[idx] = (half_t)(tanhf_(cn) * og);
    }
}

// ---------------------------------------------------------------------------
// Final projection + softmax. One block per batch row; thread j owns logit j.
// ---------------------------------------------------------------------------
__global__ __launch_bounds__(128) void lstm_final(
    const half_t* __restrict__ h, const float* __restrict__ Wph,
    const float* __restrict__ bph, float* __restrict__ out)
{
    __shared__ float hrow[HDIM];
    __shared__ float es[ODIM];
    __shared__ float logits[ODIM];
    const int b = blockIdx.x, j = threadIdx.x;

    for (int k = j; k < HDIM; k += ODIM) hrow[k] = (float)h[((size_t)b << 10) + k];
    __syncthreads();

    const float4* wp = (const float4*)(Wph + (size_t)j * HDIM);
    float s = 0.0f;
#pragma unroll 4
    for (int k4 = 0; k4 < HDIM / 4; ++k4) {
        const float4 wv = wp[k4];
        s += wv.x * hrow[k4 * 4 + 0] + wv.y * hrow[k4 * 4 + 1]
           + wv.z * hrow[k4 * 4 + 2] + wv.w * hrow[k4 * 4 + 3];
    }
    s += bph[j];
    logits[j] = s;
    __syncthreads();

    float mx = -1e30f;
    for (int i = 0; i < ODIM; ++i) mx = fmaxf(mx, logits[i]);
    const float e = __expf(s - mx);
    es[j] = e;
    __syncthreads();
    float sum = 0.0f;
    for (int i = 0; i < ODIM; ++i) sum += es[i];
    out[b * ODIM + j] = e / sum;
}

// ---------------------------------------------------------------------------
extern "C" void kernel_launch(void* const* d_in, const int* in_sizes, int n_in,
                              void* d_out, int out_size, void* d_ws, size_t ws_size,
                              hipStream_t stream) {
    const float* x   = (const float*)d_in[0];
    const float* Wfx = (const float*)d_in[1];
    const float* bfx = (const float*)d_in[2];
    const float* Wfh = (const float*)d_in[3];
    const float* bfh = (const float*)d_in[4];
    const float* Wix = (const float*)d_in[5];
    const float* bix = (const float*)d_in[6];
    const float* Wih = (const float*)d_in[7];
    const float* bih = (const float*)d_in[8];
    const float* Wgx = (const float*)d_in[9];
    const float* bgx = (const float*)d_in[10];
    const float* Wgh = (const float*)d_in[11];
    const float* bgh = (const float*)d_in[12];
    const float* Wox = (const float*)d_in[13];
    const float* box = (const float*)d_in[14];
    const float* Woh = (const float*)d_in[15];
    const float* boh = (const float*)d_in[16];
    const float* Wph = (const float*)d_in[17];
    const float* bph = (const float*)d_in[18];

    // Workspace layout (~10.1 MB total)
    char* ws = (char*)d_ws;
    half_t* Whh  = (half_t*)(ws);                       // 4*1024*1024 f16 = 8 MB
    half_t* h0   = (half_t*)(ws + 8388608);             // 512 KB
    half_t* h1   = (half_t*)(ws + 8912896);             // 512 KB
    float*  c    = (float*) (ws + 9437184);             // 1 MB
    float*  bias = (float*) (ws + 10485760);            // 16 KB
    float*  wx   = (float*) (ws + 10502144);            // 16 KB

    lstm_init<<<256, 256, 0, stream>>>(
        Wfh, Wih, Wgh, Woh, Wfx, Wix, Wgx, Wox,
        bfx, bix, bgx, box, bfh, bih, bgh, boh,
        Whh, h0, c, bias, wx);

    half_t* hb[2] = {h0, h1};
    for (int t = 0; t < SEQ; ++t) {
        lstm_step<<<dim3(4, 64), 256, 0, stream>>>(
            t, x, Whh, bias, wx, hb[t & 1], hb[(t + 1) & 1], c);
    }
    // after t=127 the latest h is in hb[0] (128 even)
    lstm_final<<<BATCH, ODIM, 0, stream>>>(hb[0], Wph, bph, (float*)d_out);
}

// Round 2
// 1719.986 us; speedup vs baseline: 1.2100x; 1.2100x over previous
//
#include <hip/hip_runtime.h>
#include <hip/hip_fp16.h>
#include <cstdint>
#include <cstddef>

#define SEQ   128
#define BATCH 256
#define HDIM  1024
#define ODIM  128

typedef _Float16 half_t;
typedef _Float16 half8 __attribute__((ext_vector_type(8)));
typedef float    f32x4 __attribute__((ext_vector_type(4)));

__device__ __forceinline__ float sigmoidf_(float z) {
    return 1.0f / (1.0f + __expf(-z));
}
__device__ __forceinline__ float tanhf_(float z) {
    z = fminf(fmaxf(z, -30.0f), 30.0f);
    float e = __expf(2.0f * z);
    return (e - 1.0f) / (e + 1.0f);
}

// ---------------------------------------------------------------------------
// Init: Wh (4x 1024x1024 fp32) -> f16 gate-major [g][u][k]; fused bias
// (bx+bh) and x-weight per gate-unit; zero h0 (f16) and c (fp32).
// Re-run every call: harness re-poisons d_ws before each timed launch.
// ---------------------------------------------------------------------------
__global__ __launch_bounds__(256) void lstm_init(
    const float* __restrict__ Wfh, const float* __restrict__ Wih,
    const float* __restrict__ Wgh, const float* __restrict__ Woh,
    const float* __restrict__ Wfx, const float* __restrict__ Wix,
    const float* __restrict__ Wgx, const float* __restrict__ Wox,
    const float* __restrict__ bfx, const float* __restrict__ bix,
    const float* __restrict__ bgx, const float* __restrict__ box,
    const float* __restrict__ bfh, const float* __restrict__ bih,
    const float* __restrict__ bgh, const float* __restrict__ boh,
    half_t* __restrict__ Whh, half_t* __restrict__ h0, float* __restrict__ c,
    float* __restrict__ bias, float* __restrict__ wx)
{
    const int tid = blockIdx.x * blockDim.x + threadIdx.x;
    const int nth = gridDim.x * blockDim.x;

    for (int i = tid; i < (4 * HDIM * HDIM) / 4; i += nth) {
        const int e = i * 4;
        const int g = e >> 20;
        const int r = e & ((1 << 20) - 1);
        const float* src = (g == 0) ? Wfh : (g == 1) ? Wih : (g == 2) ? Wgh : Woh;
        const float4 v = ((const float4*)src)[r >> 2];
        half_t* dst = Whh + e;
        dst[0] = (half_t)v.x; dst[1] = (half_t)v.y;
        dst[2] = (half_t)v.z; dst[3] = (half_t)v.w;
    }

    int4 z4; z4.x = z4.y = z4.z = z4.w = 0;
    for (int i = tid; i < (BATCH * HDIM) / 8; i += nth) ((int4*)h0)[i] = z4;
    for (int i = tid; i < (BATCH * HDIM) / 4; i += nth) ((int4*)c)[i]  = z4;

    for (int i = tid; i < 4 * HDIM; i += nth) {
        const int g = i >> 10, u = i & (HDIM - 1);
        const float* bx  = (g == 0) ? bfx : (g == 1) ? bix : (g == 2) ? bgx : box;
        const float* bh  = (g == 0) ? bfh : (g == 1) ? bih : (g == 2) ? bgh : boh;
        const float* wxs = (g == 0) ? Wfx : (g == 1) ? Wix : (g == 2) ? Wgx : Wox;
        bias[i] = bx[u] + bh[u];
        wx[i]   = wxs[u];
    }
}

// ---------------------------------------------------------------------------
// One LSTM step, barrier-free K-loop. 256 blocks x 256 threads.
// Block blk: by = blk&63 (u-tile, 16 units), bx = blk>>6 (batch tile, 64 rows)
//   -> the 4 blocks sharing a weight slice have equal (blk mod 8) -> same XCD.
// Wave w owns k in [256w, 256w+256): computes the full 64x64 (batch x 4-gate)
// partial product with 16 MFMA accumulators; A and B fragments are loaded
// straight from global in MFMA layout (16 contiguous bytes/lane, L2-hot).
// One __syncthreads total: cross-wave K-reduce + fused gate epilogue via LDS.
// ---------------------------------------------------------------------------
__global__ __launch_bounds__(256, 1) void lstm_step(
    int t, const float* __restrict__ x,
    const half_t* __restrict__ Whh, const float* __restrict__ bias,
    const float* __restrict__ wx,
    const half_t* __restrict__ hin, half_t* __restrict__ hout,
    float* __restrict__ c)
{
    __shared__ float P[4][64][68];   // [wave][col(g*16+u)][row(batch), pad 68] = 68 KB

    const int tid  = threadIdx.x;
    const int w    = tid >> 6;
    const int lane = tid & 63;
    const int l15  = lane & 15;
    const int q    = lane >> 4;

    const int blk = blockIdx.x;
    const int by  = blk & 63;        // u-tile
    const int bx  = blk >> 6;        // batch tile
    const int m0  = bx << 6;
    const int u0  = by << 4;
    const int k0  = w << 8;          // wave's K-quarter base

    f32x4 acc[4][4] = {};            // [row-tile][gate]

    // A frag: A[m = l15][k = k0+kk + q*8 + j], rows m0 + r*16 + l15
    const half_t* ap = hin + (size_t)(m0 + l15) * HDIM + k0 + (q << 3);
    // B frag: B[n = l15][k = k0+kk + q*8 + j], n = gate g, unit u0 + l15
    const half_t* bp = Whh + (size_t)(u0 + l15) * HDIM + k0 + (q << 3);

#pragma unroll
    for (int kk = 0; kk < 256; kk += 32) {
        half8 a[4], b[4];
#pragma unroll
        for (int r = 0; r < 4; ++r)
            a[r] = *(const half8*)(ap + (r << 14) + kk);            // r*16*HDIM
#pragma unroll
        for (int g = 0; g < 4; ++g)
            b[g] = *(const half8*)(bp + ((size_t)g << 20) + kk);    // g*HDIM*HDIM
#pragma unroll
        for (int r = 0; r < 4; ++r)
#pragma unroll
            for (int g = 0; g < 4; ++g)
                acc[r][g] = __builtin_amdgcn_mfma_f32_16x16x32_f16(
                    a[r], b[g], acc[r][g], 0, 0, 0);
    }

    // Partial C tiles -> LDS. C/D: col = lane&15, row = (lane>>4)*4 + reg.
    // [col][row] layout makes the 4 regs contiguous -> ds_write_b128.
#pragma unroll
    for (int r = 0; r < 4; ++r)
#pragma unroll
        for (int g = 0; g < 4; ++g)
            *(f32x4*)&P[w][(g << 4) + l15][(r << 4) + (q << 2)] = acc[r][g];

    __syncthreads();

    // K-reduce (sum 4 waves) + gate fusion. Thread: u = tid>>4, rows b0..b0+3.
    const int u  = tid >> 4;
    const int b0 = (tid & 15) << 2;
    f32x4 z[4];
#pragma unroll
    for (int g = 0; g < 4; ++g) {
        f32x4 s = *(const f32x4*)&P[0][(g << 4) + u][b0];
#pragma unroll
        for (int ww = 1; ww < 4; ++ww)
            s += *(const f32x4*)&P[ww][(g << 4) + u][b0];
        z[g] = s;
    }

    const int ug = u0 + u;
    const float bf = bias[0 * HDIM + ug], bi = bias[1 * HDIM + ug];
    const float bg = bias[2 * HDIM + ug], bo = bias[3 * HDIM + ug];
    const float wf = wx[0 * HDIM + ug],  wi = wx[1 * HDIM + ug];
    const float wg = wx[2 * HDIM + ug],  wo = wx[3 * HDIM + ug];

#pragma unroll
    for (int e = 0; e < 4; ++e) {
        const int b = m0 + b0 + e;
        const float xv = x[t * BATCH + b];
        const float zf = z[0][e] + xv * wf + bf;
        const float zi = z[1][e] + xv * wi + bi;
        const float zg = z[2][e] + xv * wg + bg;
        const float zo = z[3][e] + xv * wo + bo;
        const float fg = sigmoidf_(zf);
        const float ig = sigmoidf_(zi);
        const float gg = tanhf_(zg);
        const float og = sigmoidf_(zo);
        const size_t idx = ((size_t)b << 10) + ug;
        const float cn = gg * ig + c[idx] * fg;
        c[idx] = cn;
        hout[idx] = (half_t)(tanhf_(cn) * og);
    }
}

// ---------------------------------------------------------------------------
// Final projection + softmax. One block per batch row; thread j owns logit j.
// ---------------------------------------------------------------------------
__global__ __launch_bounds__(128) void lstm_final(
    const half_t* __restrict__ h, const float* __restrict__ Wph,
    const float* __restrict__ bph, float* __restrict__ out)
{
    __shared__ float hrow[HDIM];
    __shared__ float es[ODIM];
    __shared__ float logits[ODIM];
    const int b = blockIdx.x, j = threadIdx.x;

    for (int k = j; k < HDIM; k += ODIM) hrow[k] = (float)h[((size_t)b << 10) + k];
    __syncthreads();

    const float4* wp = (const float4*)(Wph + (size_t)j * HDIM);
    float s = 0.0f;
#pragma unroll 4
    for (int k4 = 0; k4 < HDIM / 4; ++k4) {
        const float4 wv = wp[k4];
        s += wv.x * hrow[k4 * 4 + 0] + wv.y * hrow[k4 * 4 + 1]
           + wv.z * hrow[k4 * 4 + 2] + wv.w * hrow[k4 * 4 + 3];
    }
    s += bph[j];
    logits[j] = s;
    __syncthreads();

    float mx = -1e30f;
    for (int i = 0; i < ODIM; ++i) mx = fmaxf(mx, logits[i]);
    const float e = __expf(s - mx);
    es[j] = e;
    __syncthreads();
    float sum = 0.0f;
    for (int i = 0; i < ODIM; ++i) sum += es[i];
    out[b * ODIM + j] = e / sum;
}

// ---------------------------------------------------------------------------
extern "C" void kernel_launch(void* const* d_in, const int* in_sizes, int n_in,
                              void* d_out, int out_size, void* d_ws, size_t ws_size,
                              hipStream_t stream) {
    const float* x   = (const float*)d_in[0];
    const float* Wfx = (const float*)d_in[1];
    const float* bfx = (const float*)d_in[2];
    const float* Wfh = (const float*)d_in[3];
    const float* bfh = (const float*)d_in[4];
    const float* Wix = (const float*)d_in[5];
    const float* bix = (const float*)d_in[6];
    const float* Wih = (const float*)d_in[7];
    const float* bih = (const float*)d_in[8];
    const float* Wgx = (const float*)d_in[9];
    const float* bgx = (const float*)d_in[10];
    const float* Wgh = (const float*)d_in[11];
    const float* bgh = (const float*)d_in[12];
    const float* Wox = (const float*)d_in[13];
    const float* box = (const float*)d_in[14];
    const float* Woh = (const float*)d_in[15];
    const float* boh = (const float*)d_in[16];
    const float* Wph = (const float*)d_in[17];
    const float* bph = (const float*)d_in[18];

    char* ws = (char*)d_ws;
    half_t* Whh  = (half_t*)(ws);                       // 8 MB
    half_t* h0   = (half_t*)(ws + 8388608);             // 512 KB
    half_t* h1   = (half_t*)(ws + 8912896);             // 512 KB
    float*  c    = (float*) (ws + 9437184);             // 1 MB
    float*  bias = (float*) (ws + 10485760);            // 16 KB
    float*  wx   = (float*) (ws + 10502144);            // 16 KB

    lstm_init<<<256, 256, 0, stream>>>(
        Wfh, Wih, Wgh, Woh, Wfx, Wix, Wgx, Wox,
        bfx, bix, bgx, box, bfh, bih, bgh, boh,
        Whh, h0, c, bias, wx);

    half_t* hb[2] = {h0, h1};
    for (int t = 0; t < SEQ; ++t) {
        lstm_step<<<256, 256, 0, stream>>>(
            t, x, Whh, bias, wx, hb[t & 1], hb[(t + 1) & 1], c);
    }
    lstm_final<<<BATCH, ODIM, 0, stream>>>(hb[0], Wph, bph, (float*)d_out);
}